// Round 9
// baseline (803.428 us; speedup 1.0000x reference)
//
#include <hip/hip_runtime.h>

#define NG 4
#define NN 50000
#define NE 800000
#define NC 128
#define NB 196              // ceil(NN/256) buckets of 256 nodes per graph
#define NBT (NG * NB)       // 784 total buckets
#define CAPB 48             // LDS bin capacity in pass B (lambda~21, +6 sigma)
#define LBS (NB + 1)        // lbin stride 197 (odd -> conflict-free flush)

typedef _Float16 half8 __attribute__((ext_vector_type(8)));
typedef _Float16 half4 __attribute__((ext_vector_type(4)));
typedef _Float16 half2_t __attribute__((ext_vector_type(2)));
typedef float f32x4 __attribute__((ext_vector_type(4)));

// ---------------------------------------------------------------- utilities
__global__ __launch_bounds__(256) void zero_kernel(int* __restrict__ a, int n) {
  int i = blockIdx.x * blockDim.x + threadIdx.x;
  if (i < n) a[i] = 0;
}

// ------------------------------------------------ CSR build, bucketed sort
// Pass A: histogram of dst>>8 per graph. Coalesced reads, LDS atomics,
// one global atomic per (wg,bucket).
__global__ __launch_bounds__(256) void bucket_count(
    const int* __restrict__ ei, int* __restrict__ bktCnt) {
  __shared__ int lcnt[NB];
  int g = blockIdx.y;
  for (int i = threadIdx.x; i < NB; i += 256) lcnt[i] = 0;
  __syncthreads();
  const int* dstp = ei + (size_t)g * 2 * NE + NE;
  int e0 = blockIdx.x * 16384;
  for (int t = threadIdx.x; t < 16384; t += 256) {
    int e = e0 + t;
    if (e < NE) atomicAdd(&lcnt[dstp[e] >> 8], 1);
  }
  __syncthreads();
  for (int i = threadIdx.x; i < NB; i += 256)
    if (lcnt[i]) atomicAdd(&bktCnt[g * NB + i], lcnt[i]);
}

// Scan of all 784 bucket counts (g-major: graph g's region starts at g*NE).
__global__ __launch_bounds__(1024) void scan_buckets(
    const int* __restrict__ bktCnt, int* __restrict__ bktBase,
    int* __restrict__ bktCur) {
  __shared__ int wsum[16];
  int tid = threadIdx.x, lane = tid & 63, wv = tid >> 6;
  int v = (tid < NBT) ? bktCnt[tid] : 0;
  int incl = v;
  #pragma unroll
  for (int d2 = 1; d2 < 64; d2 <<= 1) {
    int t = __shfl_up(incl, d2, 64);
    if (lane >= d2) incl += t;
  }
  if (lane == 63) wsum[wv] = incl;
  __syncthreads();
  if (tid == 0) {
    int s = 0;
    #pragma unroll
    for (int w = 0; w < 16; ++w) { int t = wsum[w]; wsum[w] = s; s += t; }
  }
  __syncthreads();
  int excl = wsum[wv] + incl - v;
  if (tid <= NBT) bktBase[tid] = excl;   // tid==NBT -> total (=NG*NE)
  if (tid < NBT) bktCur[tid] = excl;
}

// Pass B: scatter packed records (dst_local<<16 | src) into bucket-grouped
// rec[]. LDS bins laid out [pos][bucket] (stride 197 -> conflict-free flush
// reads); bases for all buckets reserved in ONE parallel phase, then flush
// is pure LDS-read + pipelined global write.
__global__ __launch_bounds__(256) void bucket_scatter(
    const int* __restrict__ ei, int* __restrict__ bktCur,
    unsigned int* __restrict__ rec) {
  __shared__ int lcnt[NB];
  __shared__ int lbase[NB];
  __shared__ unsigned int lbin[CAPB * LBS];   // ~37.8 KB
  int g = blockIdx.y;
  int tid = threadIdx.x;
  for (int i = tid; i < NB; i += 256) lcnt[i] = 0;
  __syncthreads();
  const int* srcp = ei + (size_t)g * 2 * NE;
  const int* dstp = srcp + NE;
  int e0 = blockIdx.x * 4096;
  for (int t = tid; t < 4096; t += 256) {
    int e = e0 + t;
    if (e < NE) {
      int s = srcp[e], d = dstp[e];
      int b = d >> 8;
      unsigned int r = ((unsigned int)(d & 255) << 16) | (unsigned int)s;
      int pos = atomicAdd(&lcnt[b], 1);
      if (pos < CAPB) lbin[pos * LBS + b] = r;
      else { int gp = atomicAdd(&bktCur[g * NB + b], 1); rec[gp] = r; }  // rare
    }
  }
  __syncthreads();
  // reserve: one atomic per bucket, all in flight at once
  if (tid < NB) {
    int n = lcnt[tid]; if (n > CAPB) n = CAPB;
    lbase[tid] = n ? atomicAdd(&bktCur[g * NB + tid], n) : 0;
  }
  __syncthreads();
  // flush: no atomics, stores pipeline freely
  int lane = tid & 63, wv = tid >> 6;
  for (int b = wv; b < NB; b += 4) {
    int n = lcnt[b]; if (n > CAPB) n = CAPB;
    if (lane < n) rec[lbase[b] + lane] = lbin[lane * LBS + b];
  }
}

// Pass C: per (graph,bucket) build exact CSR: LDS count -> scan -> rank.
// col scatter stays inside the bucket's ~8KB region. Emits off, dis.
__global__ __launch_bounds__(256) void build_csr(
    const unsigned int* __restrict__ rec, const int* __restrict__ bktBase,
    unsigned short* __restrict__ col, int* __restrict__ off,
    float* __restrict__ dis) {
  __shared__ int cnt[256];
  __shared__ int offv[256];
  __shared__ int cnt2[256];
  __shared__ int wsum[4];
  int g = blockIdx.y, b = blockIdx.x;
  int idx = g * NB + b;
  int rb = bktBase[idx], re = bktBase[idx + 1];
  int tid = threadIdx.x;
  cnt[tid] = 0;
  __syncthreads();
  for (int j = rb + tid; j < re; j += 256)
    atomicAdd(&cnt[(rec[j] >> 16) & 255], 1);
  __syncthreads();
  int lane = tid & 63, wv = tid >> 6;
  int v = cnt[tid], incl = v;
  #pragma unroll
  for (int d2 = 1; d2 < 64; d2 <<= 1) {
    int t = __shfl_up(incl, d2, 64);
    if (lane >= d2) incl += t;
  }
  if (lane == 63) wsum[wv] = incl;
  __syncthreads();
  if (tid == 0) {
    int s = 0;
    #pragma unroll
    for (int w = 0; w < 4; ++w) { int t = wsum[w]; wsum[w] = s; s += t; }
  }
  __syncthreads();
  int excl = wsum[wv] + incl - v;
  offv[tid] = excl;
  cnt2[tid] = 0;
  int node = b * 256 + tid;
  if (node < NN) {
    off[g * (NN + 1) + node] = rb + excl;
    dis[(size_t)g * NN + node] = rsqrtf((float)(v + 1));  // +1 self loop
  }
  if (b == NB - 1 && tid == 0) off[g * (NN + 1) + NN] = re;
  __syncthreads();
  for (int j = rb + tid; j < re; j += 256) {
    unsigned int r = rec[j];
    int dl = (r >> 16) & 255;
    int p = rb + offv[dl] + atomicAdd(&cnt2[dl], 1);
    col[p] = (unsigned short)(r & 0xFFFF);
  }
}

// ---------------------------------------------------- MFMA GEMM  h'=(x@W)*dis
// Block 256 (4 waves), tile 128 rows x 128 cols, K=128 in 4 steps of 32.
// Split precision: x = xhi+xlo (fp16), W = Whi+Wlo (fp16), 3 MFMAs/frag.
// B-tile nb covers true cols {lr*8+nb} -> each lane's 8 acc cols are
// CONTIGUOUS (lr*8..lr*8+7) -> h' store is TRUE row-major (no permute).
// LDS swizzle key (lr^nb)&7: read 2-way, write same as before.
__global__ __launch_bounds__(256) void gemm_mfma_kernel(
    const float* __restrict__ x, const float* __restrict__ W,
    const float* __restrict__ dis, _Float16* __restrict__ h) {
  __shared__ _Float16 Wt[2][128 * 128];
  int g = blockIdx.y;
  int row0 = blockIdx.x * 128;
  int tid = threadIdx.x;
  int lane = tid & 63;
  int wv = tid >> 6;
  int kc = lane >> 4;
  int lr = lane & 15;
  const float* Wg = W + (size_t)g * NC * NC;
  const float* xg = x + (size_t)g * NN * NC;

  {
    int n = tid & 127;
    int kq = (tid >> 7) & 1;
    int key = ((n >> 3) ^ n) & 7;
    #pragma unroll
    for (int iter = 0; iter < 16; ++iter) {
      int k4 = iter * 8 + kq * 4;
      float w0 = Wg[(size_t)(k4 + 0) * NC + n];
      float w1 = Wg[(size_t)(k4 + 1) * NC + n];
      float w2 = Wg[(size_t)(k4 + 2) * NC + n];
      float w3 = Wg[(size_t)(k4 + 3) * NC + n];
      half4 hi, lo;
      hi[0] = (_Float16)w0; lo[0] = (_Float16)(w0 - (float)hi[0]);
      hi[1] = (_Float16)w1; lo[1] = (_Float16)(w1 - (float)hi[1]);
      hi[2] = (_Float16)w2; lo[2] = (_Float16)(w2 - (float)hi[2]);
      hi[3] = (_Float16)w3; lo[3] = (_Float16)(w3 - (float)hi[3]);
      int base = n * 128 + ((iter ^ key) << 3) + kq * 4;
      *(half4*)&Wt[0][base] = hi;
      *(half4*)&Wt[1][base] = lo;
    }
  }
  __syncthreads();

  f32x4 acc[2][8];
  #pragma unroll
  for (int mb = 0; mb < 2; ++mb)
    #pragma unroll
    for (int nb = 0; nb < 8; ++nb)
      acc[mb][nb] = (f32x4){0.f, 0.f, 0.f, 0.f};

  for (int kstep = 0; kstep < 4; ++kstep) {
    half8 ah[2], al[2];
    #pragma unroll
    for (int mb = 0; mb < 2; ++mb) {
      int row = row0 + wv * 32 + mb * 16 + lr;
      if (row > NN - 1) row = NN - 1;
      const float* xp = xg + (size_t)row * NC + kstep * 32 + kc * 8;
      float4 v0 = *(const float4*)xp;
      float4 v1 = *(const float4*)(xp + 4);
      float vv0 = v0.x, vv1 = v0.y, vv2 = v0.z, vv3 = v0.w;
      float vv4 = v1.x, vv5 = v1.y, vv6 = v1.z, vv7 = v1.w;
      _Float16 t;
      t = (_Float16)vv0; ah[mb][0] = t; al[mb][0] = (_Float16)(vv0 - (float)t);
      t = (_Float16)vv1; ah[mb][1] = t; al[mb][1] = (_Float16)(vv1 - (float)t);
      t = (_Float16)vv2; ah[mb][2] = t; al[mb][2] = (_Float16)(vv2 - (float)t);
      t = (_Float16)vv3; ah[mb][3] = t; al[mb][3] = (_Float16)(vv3 - (float)t);
      t = (_Float16)vv4; ah[mb][4] = t; al[mb][4] = (_Float16)(vv4 - (float)t);
      t = (_Float16)vv5; ah[mb][5] = t; al[mb][5] = (_Float16)(vv5 - (float)t);
      t = (_Float16)vv6; ah[mb][6] = t; al[mb][6] = (_Float16)(vv6 - (float)t);
      t = (_Float16)vv7; ah[mb][7] = t; al[mb][7] = (_Float16)(vv7 - (float)t);
    }
    #pragma unroll
    for (int nb = 0; nb < 8; ++nb) {
      int n = lr * 8 + nb;                 // true col this lane/tile handles
      int key = ((n >> 3) ^ n) & 7;        // = (lr ^ nb) & 7
      int chunk = kstep * 4 + kc;
      int boff = n * 128 + ((chunk ^ key) << 3);
      half8 bh = *(const half8*)&Wt[0][boff];
      half8 bl = *(const half8*)&Wt[1][boff];
      #pragma unroll
      for (int mb = 0; mb < 2; ++mb) {
        acc[mb][nb] = __builtin_amdgcn_mfma_f32_16x16x32_f16(ah[mb], bh, acc[mb][nb], 0, 0, 0);
        acc[mb][nb] = __builtin_amdgcn_mfma_f32_16x16x32_f16(al[mb], bh, acc[mb][nb], 0, 0, 0);
        acc[mb][nb] = __builtin_amdgcn_mfma_f32_16x16x32_f16(ah[mb], bl, acc[mb][nb], 0, 0, 0);
      }
    }
  }

  const float* disg = dis + (size_t)g * NN;
  _Float16* hg = h + (size_t)g * NN * NC;
  #pragma unroll
  for (int mb = 0; mb < 2; ++mb) {
    #pragma unroll
    for (int reg = 0; reg < 4; ++reg) {
      int row = row0 + wv * 32 + mb * 16 + kc * 4 + reg;
      if (row < NN) {
        float dsc = disg[row];
        half8 o;
        #pragma unroll
        for (int nb = 0; nb < 8; ++nb)
          o[nb] = (_Float16)(acc[mb][nb][reg] * dsc);   // col lr*8+nb
        *(half8*)(hg + (size_t)row * NC + lr * 8) = o;  // TRUE row-major
      }
    }
  }
}

// --------------------------------------------- aggregation: gather over CSR
// out[i] = dis[i]*(h'[i] + sum_{e: dst=i} h'[src_e]) + b
// ONE GRAPH per dispatch; 4 column-quarters (64B granule) pinned to XCD
// pairs via bid&7 -> per-XCD gather working set = 3.2MB < 4MB L2.
// 16 lanes per (node,quarter), half2 (4B) per lane, 4-deep unrolled chains.
__global__ __launch_bounds__(256) void agg_kernel(
    const _Float16* __restrict__ h, const int* __restrict__ off,
    const unsigned short* __restrict__ col, const float* __restrict__ dis,
    const float* __restrict__ b, float* __restrict__ out, int g) {
  int bid = blockIdx.x;
  int q = (bid >> 1) & 3;                          // quarter -> XCD pair
  int chunk = ((bid >> 3) << 1) | (bid & 1);       // node chunk within graph
  int node = chunk * 16 + (threadIdx.x >> 4);
  if (node >= NN) return;
  int l = threadIdx.x & 15;
  int co = q * 32 + l * 2;                         // true column offset
  const _Float16* hg = h + (size_t)g * NN * NC + co;
  half2_t v = *(const half2_t*)(hg + (size_t)node * NC);  // self loop
  float ax0 = (float)v[0], ay0 = (float)v[1];
  float ax1 = 0.f, ay1 = 0.f, ax2 = 0.f, ay2 = 0.f, ax3 = 0.f, ay3 = 0.f;
  int s = off[g * (NN + 1) + node];
  int e = off[g * (NN + 1) + node + 1];
  int j = s;
  for (; j + 4 <= e; j += 4) {
    int c0 = col[j], c1 = col[j + 1], c2 = col[j + 2], c3 = col[j + 3];
    half2_t v0 = *(const half2_t*)(hg + (size_t)c0 * NC);
    half2_t v1 = *(const half2_t*)(hg + (size_t)c1 * NC);
    half2_t v2 = *(const half2_t*)(hg + (size_t)c2 * NC);
    half2_t v3 = *(const half2_t*)(hg + (size_t)c3 * NC);
    ax0 = fmaf((float)v0[0], 1.f, ax0); ay0 = fmaf((float)v0[1], 1.f, ay0);
    ax1 = fmaf((float)v1[0], 1.f, ax1); ay1 = fmaf((float)v1[1], 1.f, ay1);
    ax2 = fmaf((float)v2[0], 1.f, ax2); ay2 = fmaf((float)v2[1], 1.f, ay2);
    ax3 = fmaf((float)v3[0], 1.f, ax3); ay3 = fmaf((float)v3[1], 1.f, ay3);
  }
  for (; j < e; ++j) {
    half2_t vr = *(const half2_t*)(hg + (size_t)col[j] * NC);
    ax0 = fmaf((float)vr[0], 1.f, ax0); ay0 = fmaf((float)vr[1], 1.f, ay0);
  }
  float dn = dis[g * NN + node];
  float bx = b[(size_t)g * NC + co];
  float by = b[(size_t)g * NC + co + 1];
  float2 o;
  o.x = (ax0 + ax1 + ax2 + ax3) * dn + bx;
  o.y = (ay0 + ay1 + ay2 + ay3) * dn + by;
  *(float2*)(out + ((size_t)g * NN + node) * NC + co) = o;   // 128B coalesced
}

// ---------------------------------------------------------------- launcher
extern "C" void kernel_launch(void* const* d_in, const int* in_sizes, int n_in,
                              void* d_out, int out_size, void* d_ws, size_t ws_size,
                              hipStream_t stream) {
  const float* x  = (const float*)d_in[0];
  const int*   ei = (const int*)d_in[1];    // int64 narrowed to int32
  const float* W1 = (const float*)d_in[2];
  const float* b1 = (const float*)d_in[3];
  const float* W2 = (const float*)d_in[4];
  const float* b2 = (const float*)d_in[5];
  const float* W3 = (const float*)d_in[6];
  const float* b3 = (const float*)d_in[7];
  float* out = (float*)d_out;

  char* ws = (char*)d_ws;
  size_t p = 0;
  auto carve = [&](size_t bytes) -> char* {
    char* r = ws + p;
    p += (bytes + 255) & ~(size_t)255;
    return r;
  };
  int*            bktCnt  = (int*)           carve((size_t)NBT * 4);
  int*            bktBase = (int*)           carve((size_t)(NBT + 1) * 4);
  int*            bktCur  = (int*)           carve((size_t)NBT * 4);
  unsigned int*   rec     = (unsigned int*)  carve((size_t)NG * NE * 4);
  unsigned short* col     = (unsigned short*)carve((size_t)NG * NE * 2);
  int*            off     = (int*)           carve((size_t)NG * (NN + 1) * 4);
  float*          dis     = (float*)         carve((size_t)NG * NN * 4);
  _Float16*       hbuf    = (_Float16*)      carve((size_t)NG * NN * NC * 2);

  zero_kernel<<<(NBT + 255) / 256, 256, 0, stream>>>(bktCnt, NBT);
  bucket_count<<<dim3((NE + 16383) / 16384, NG), 256, 0, stream>>>(ei, bktCnt);
  scan_buckets<<<1, 1024, 0, stream>>>(bktCnt, bktBase, bktCur);
  bucket_scatter<<<dim3((NE + 4095) / 4096, NG), 256, 0, stream>>>(ei, bktCur, rec);
  build_csr<<<dim3(NB, NG), 256, 0, stream>>>(rec, bktBase, col, off, dis);

  dim3 ggrid((NN + 127) / 128, NG);
  int  agrid = 1563 * 8;   // (node-chunk x parity) x (quarter pairs): 12504

  // layer 1
  gemm_mfma_kernel<<<ggrid, 256, 0, stream>>>(x, W1, dis, hbuf);
  for (int g = 0; g < NG; ++g)
    agg_kernel<<<agrid, 256, 0, stream>>>(hbuf, off, col, dis, b1, out, g);
  // layer 2 (agg reads only hbuf/CSR, overwrite of out is safe)
  gemm_mfma_kernel<<<ggrid, 256, 0, stream>>>(out, W2, dis, hbuf);
  for (int g = 0; g < NG; ++g)
    agg_kernel<<<agrid, 256, 0, stream>>>(hbuf, off, col, dis, b2, out, g);
  // layer 3
  gemm_mfma_kernel<<<ggrid, 256, 0, stream>>>(out, W3, dis, hbuf);
  for (int g = 0; g < NG; ++g)
    agg_kernel<<<agrid, 256, 0, stream>>>(hbuf, off, col, dis, b3, out, g);
}

// Round 10
// 516.541 us; speedup vs baseline: 1.5554x; 1.5554x over previous
//
#include <hip/hip_runtime.h>

#define NG 4
#define NN 50000
#define NE 800000
#define NC 128
#define NB 196              // ceil(NN/256) buckets of 256 nodes per graph
#define NBT (NG * NB)       // 784 total buckets
#define CAPB 48             // LDS bin capacity in pass B (lambda~21, +6 sigma)
#define LBS (NB + 1)        // lbin stride 197 (odd -> conflict-free flush)
#define CAPQ 4608           // fixed bucket capacity (lambda 4096, +8 sigma)

typedef _Float16 half8 __attribute__((ext_vector_type(8)));
typedef _Float16 half4 __attribute__((ext_vector_type(4)));
typedef float f32x4 __attribute__((ext_vector_type(4)));

// ---------------------------------------------------------------- utilities
__global__ __launch_bounds__(256) void init_cursors(int* __restrict__ bktCur) {
  int i = blockIdx.x * blockDim.x + threadIdx.x;
  if (i < NBT) bktCur[i] = i * CAPQ;
}

// ------------------------------------------------ CSR build, bucketed sort
// Single pass: scatter packed records (dst_local<<16 | src) into
// fixed-capacity bucket slots rec[idx*CAPQ ..]. LDS bins [pos][bucket]
// (stride 197 -> conflict-free flush); per-bucket base reserved in ONE
// parallel atomic phase; flush is pure LDS-read + pipelined global write.
__global__ __launch_bounds__(256) void bucket_scatter(
    const int* __restrict__ ei, int* __restrict__ bktCur,
    unsigned int* __restrict__ rec) {
  __shared__ int lcnt[NB];
  __shared__ int lbase[NB];
  __shared__ unsigned int lbin[CAPB * LBS];   // ~37.8 KB
  int g = blockIdx.y;
  int tid = threadIdx.x;
  for (int i = tid; i < NB; i += 256) lcnt[i] = 0;
  __syncthreads();
  const int* srcp = ei + (size_t)g * 2 * NE;
  const int* dstp = srcp + NE;
  int e0 = blockIdx.x * 4096;
  for (int t = tid; t < 4096; t += 256) {
    int e = e0 + t;
    if (e < NE) {
      int s = srcp[e], d = dstp[e];
      int b = d >> 8;
      unsigned int r = ((unsigned int)(d & 255) << 16) | (unsigned int)s;
      int pos = atomicAdd(&lcnt[b], 1);
      if (pos < CAPB) lbin[pos * LBS + b] = r;
      else { int gp = atomicAdd(&bktCur[g * NB + b], 1); rec[gp] = r; }  // rare
    }
  }
  __syncthreads();
  // reserve: one atomic per bucket, all in flight at once
  if (tid < NB) {
    int n = lcnt[tid]; if (n > CAPB) n = CAPB;
    lbase[tid] = n ? atomicAdd(&bktCur[g * NB + tid], n) : 0;
  }
  __syncthreads();
  // flush: no atomics, stores pipeline freely
  int lane = tid & 63, wv = tid >> 6;
  for (int b = wv; b < NB; b += 4) {
    int n = lcnt[b]; if (n > CAPB) n = CAPB;
    if (lane < n) rec[lbase[b] + lane] = lbin[lane * LBS + b];
  }
}

// Per (graph,bucket): LDS count -> scan -> rank into padded col[].
// Emits off (absolute into padded col), deg, dis.
__global__ __launch_bounds__(256) void build_csr(
    const unsigned int* __restrict__ rec, const int* __restrict__ bktCur,
    unsigned short* __restrict__ col, int* __restrict__ off,
    unsigned short* __restrict__ deg, float* __restrict__ dis) {
  __shared__ int cnt[256];
  __shared__ int offv[256];
  __shared__ int cnt2[256];
  __shared__ int wsum[4];
  int g = blockIdx.y, b = blockIdx.x;
  int idx = g * NB + b;
  int rb = idx * CAPQ, re = bktCur[idx];
  int tid = threadIdx.x;
  cnt[tid] = 0;
  __syncthreads();
  for (int j = rb + tid; j < re; j += 256)
    atomicAdd(&cnt[(rec[j] >> 16) & 255], 1);
  __syncthreads();
  int lane = tid & 63, wv = tid >> 6;
  int v = cnt[tid], incl = v;
  #pragma unroll
  for (int d2 = 1; d2 < 64; d2 <<= 1) {
    int t = __shfl_up(incl, d2, 64);
    if (lane >= d2) incl += t;
  }
  if (lane == 63) wsum[wv] = incl;
  __syncthreads();
  if (tid == 0) {
    int s = 0;
    #pragma unroll
    for (int w = 0; w < 4; ++w) { int t = wsum[w]; wsum[w] = s; s += t; }
  }
  __syncthreads();
  int excl = wsum[wv] + incl - v;
  offv[tid] = excl;
  cnt2[tid] = 0;
  int node = b * 256 + tid;
  if (node < NN) {
    off[g * (NN + 1) + node] = rb + excl;
    deg[(size_t)g * NN + node] = (unsigned short)v;
    dis[(size_t)g * NN + node] = rsqrtf((float)(v + 1));  // +1 self loop
  }
  __syncthreads();
  for (int j = rb + tid; j < re; j += 256) {
    unsigned int r = rec[j];
    int dl = (r >> 16) & 255;
    int p = rb + offv[dl] + atomicAdd(&cnt2[dl], 1);
    col[p] = (unsigned short)(r & 0xFFFF);
  }
}

// ---------------------------------------------------- MFMA GEMM  h'=(x@W)*dis
// Block 256 (4 waves), tile 128 rows x 128 cols, K=128 in 4 steps of 32.
// Split precision: x = xhi+xlo (fp16), W = Whi+Wlo (fp16), 3 MFMAs/frag ->
// fp32-level accuracy on the matrix pipe.
// h' written fp16 in permuted col layout p=(c&15)*8+(c>>4): each 16-lane
// group stores one full contiguous 256B row.
__global__ __launch_bounds__(256) void gemm_mfma_kernel(
    const float* __restrict__ x, const float* __restrict__ W,
    const float* __restrict__ dis, _Float16* __restrict__ h) {
  __shared__ _Float16 Wt[2][128 * 128];
  int g = blockIdx.y;
  int row0 = blockIdx.x * 128;
  int tid = threadIdx.x;
  int lane = tid & 63;
  int wv = tid >> 6;
  int kc = lane >> 4;
  int lr = lane & 15;
  const float* Wg = W + (size_t)g * NC * NC;
  const float* xg = x + (size_t)g * NN * NC;

  {
    int n = tid & 127;
    int kq = (tid >> 7) & 1;
    #pragma unroll
    for (int iter = 0; iter < 16; ++iter) {
      int k4 = iter * 8 + kq * 4;
      float w0 = Wg[(size_t)(k4 + 0) * NC + n];
      float w1 = Wg[(size_t)(k4 + 1) * NC + n];
      float w2 = Wg[(size_t)(k4 + 2) * NC + n];
      float w3 = Wg[(size_t)(k4 + 3) * NC + n];
      half4 hi, lo;
      hi[0] = (_Float16)w0; lo[0] = (_Float16)(w0 - (float)hi[0]);
      hi[1] = (_Float16)w1; lo[1] = (_Float16)(w1 - (float)hi[1]);
      hi[2] = (_Float16)w2; lo[2] = (_Float16)(w2 - (float)hi[2]);
      hi[3] = (_Float16)w3; lo[3] = (_Float16)(w3 - (float)hi[3]);
      int base = n * 128 + ((iter ^ (n & 15)) << 3) + kq * 4;
      *(half4*)&Wt[0][base] = hi;
      *(half4*)&Wt[1][base] = lo;
    }
  }
  __syncthreads();

  f32x4 acc[2][8];
  #pragma unroll
  for (int mb = 0; mb < 2; ++mb)
    #pragma unroll
    for (int nb = 0; nb < 8; ++nb)
      acc[mb][nb] = (f32x4){0.f, 0.f, 0.f, 0.f};

  for (int kstep = 0; kstep < 4; ++kstep) {
    half8 ah[2], al[2];
    #pragma unroll
    for (int mb = 0; mb < 2; ++mb) {
      int row = row0 + wv * 32 + mb * 16 + lr;
      if (row > NN - 1) row = NN - 1;
      const float* xp = xg + (size_t)row * NC + kstep * 32 + kc * 8;
      float4 v0 = *(const float4*)xp;
      float4 v1 = *(const float4*)(xp + 4);
      float vv0 = v0.x, vv1 = v0.y, vv2 = v0.z, vv3 = v0.w;
      float vv4 = v1.x, vv5 = v1.y, vv6 = v1.z, vv7 = v1.w;
      _Float16 t;
      t = (_Float16)vv0; ah[mb][0] = t; al[mb][0] = (_Float16)(vv0 - (float)t);
      t = (_Float16)vv1; ah[mb][1] = t; al[mb][1] = (_Float16)(vv1 - (float)t);
      t = (_Float16)vv2; ah[mb][2] = t; al[mb][2] = (_Float16)(vv2 - (float)t);
      t = (_Float16)vv3; ah[mb][3] = t; al[mb][3] = (_Float16)(vv3 - (float)t);
      t = (_Float16)vv4; ah[mb][4] = t; al[mb][4] = (_Float16)(vv4 - (float)t);
      t = (_Float16)vv5; ah[mb][5] = t; al[mb][5] = (_Float16)(vv5 - (float)t);
      t = (_Float16)vv6; ah[mb][6] = t; al[mb][6] = (_Float16)(vv6 - (float)t);
      t = (_Float16)vv7; ah[mb][7] = t; al[mb][7] = (_Float16)(vv7 - (float)t);
    }
    #pragma unroll
    for (int nb = 0; nb < 8; ++nb) {
      int n = nb * 16 + lr;
      int chunk = kstep * 4 + kc;
      int boff = n * 128 + ((chunk ^ (n & 15)) << 3);
      half8 bh = *(const half8*)&Wt[0][boff];
      half8 bl = *(const half8*)&Wt[1][boff];
      #pragma unroll
      for (int mb = 0; mb < 2; ++mb) {
        acc[mb][nb] = __builtin_amdgcn_mfma_f32_16x16x32_f16(ah[mb], bh, acc[mb][nb], 0, 0, 0);
        acc[mb][nb] = __builtin_amdgcn_mfma_f32_16x16x32_f16(al[mb], bh, acc[mb][nb], 0, 0, 0);
        acc[mb][nb] = __builtin_amdgcn_mfma_f32_16x16x32_f16(ah[mb], bl, acc[mb][nb], 0, 0, 0);
      }
    }
  }

  const float* disg = dis + (size_t)g * NN;
  _Float16* hg = h + (size_t)g * NN * NC;
  #pragma unroll
  for (int mb = 0; mb < 2; ++mb) {
    #pragma unroll
    for (int reg = 0; reg < 4; ++reg) {
      int row = row0 + wv * 32 + mb * 16 + kc * 4 + reg;
      if (row < NN) {
        float dsc = disg[row];
        half8 o;
        #pragma unroll
        for (int nb = 0; nb < 8; ++nb)
          o[nb] = (_Float16)(acc[mb][nb][reg] * dsc);
        *(half8*)(hg + (size_t)row * NC + lr * 8) = o;
      }
    }
  }
}

// --------------------------------------------- aggregation: gather over CSR
// out[i] = dis[i]*(h'[i] + sum_{e: dst=i} h'[src_e]) + b
// 16 lanes per node (8 fp16 each); 8 gathers in flight, 4 accumulator sets;
// fp16->fp32 accumulate via fmaf(h,1.0f,acc) -> v_fma_mix_f32.
// XCD-graph affinity: 1-D grid, g=(bid&7)>>1 -> graph pinned to XCD pair.
#define MIXACC(A, H) A = fmaf((float)(H), 1.0f, A)
__global__ __launch_bounds__(256) void agg_kernel(
    const _Float16* __restrict__ h, const int* __restrict__ off,
    const unsigned short* __restrict__ col, const unsigned short* __restrict__ deg,
    const float* __restrict__ dis, const float* __restrict__ b,
    float* __restrict__ out) {
  int bid = blockIdx.x;
  int g = (bid & 7) >> 1;                        // graph -> XCD pair
  int sub = ((bid >> 3) << 1) | (bid & 1);       // block index within graph
  int node = sub * 16 + (threadIdx.x >> 4);
  if (sub >= NN / 16) return;
  int l = threadIdx.x & 15;
  const half8* h8 = (const half8*)(h + (size_t)g * NN * NC);
  float a0[8], a1[8], a2[8], a3[8];
  half8 v = h8[(size_t)node * 16 + l];   // self loop
  #pragma unroll
  for (int i = 0; i < 8; ++i) {
    a0[i] = (float)v[i]; a1[i] = 0.f; a2[i] = 0.f; a3[i] = 0.f;
  }
  int s = off[g * (NN + 1) + node];
  int e = s + deg[(size_t)g * NN + node];
  int j = s;
  for (; j + 8 <= e; j += 8) {
    int c0 = col[j],     c1 = col[j + 1], c2 = col[j + 2], c3 = col[j + 3];
    int c4 = col[j + 4], c5 = col[j + 5], c6 = col[j + 6], c7 = col[j + 7];
    half8 v0 = h8[(size_t)c0 * 16 + l];
    half8 v1 = h8[(size_t)c1 * 16 + l];
    half8 v2 = h8[(size_t)c2 * 16 + l];
    half8 v3 = h8[(size_t)c3 * 16 + l];
    half8 v4 = h8[(size_t)c4 * 16 + l];
    half8 v5 = h8[(size_t)c5 * 16 + l];
    half8 v6 = h8[(size_t)c6 * 16 + l];
    half8 v7 = h8[(size_t)c7 * 16 + l];
    #pragma unroll
    for (int i = 0; i < 8; ++i) {
      MIXACC(a0[i], v0[i]); MIXACC(a1[i], v1[i]);
      MIXACC(a2[i], v2[i]); MIXACC(a3[i], v3[i]);
      MIXACC(a0[i], v4[i]); MIXACC(a1[i], v5[i]);
      MIXACC(a2[i], v6[i]); MIXACC(a3[i], v7[i]);
    }
  }
  for (; j + 4 <= e; j += 4) {
    int c0 = col[j], c1 = col[j + 1], c2 = col[j + 2], c3 = col[j + 3];
    half8 v0 = h8[(size_t)c0 * 16 + l];
    half8 v1 = h8[(size_t)c1 * 16 + l];
    half8 v2 = h8[(size_t)c2 * 16 + l];
    half8 v3 = h8[(size_t)c3 * 16 + l];
    #pragma unroll
    for (int i = 0; i < 8; ++i) {
      MIXACC(a0[i], v0[i]); MIXACC(a1[i], v1[i]);
      MIXACC(a2[i], v2[i]); MIXACC(a3[i], v3[i]);
    }
  }
  for (; j < e; ++j) {
    half8 vr = h8[(size_t)col[j] * 16 + l];
    #pragma unroll
    for (int i = 0; i < 8; ++i) MIXACC(a0[i], vr[i]);
  }
  float dn = dis[g * NN + node];
  float* og = out + ((size_t)g * NN + node) * NC;
  const float* bg = b + (size_t)g * NC;
  #pragma unroll
  for (int i = 0; i < 8; ++i) {   // true col c = i*16 + l
    float val = (a0[i] + a1[i] + a2[i] + a3[i]) * dn + bg[i * 16 + l];
    og[i * 16 + l] = val;
  }
}

// ---------------------------------------------------------------- launcher
extern "C" void kernel_launch(void* const* d_in, const int* in_sizes, int n_in,
                              void* d_out, int out_size, void* d_ws, size_t ws_size,
                              hipStream_t stream) {
  const float* x  = (const float*)d_in[0];
  const int*   ei = (const int*)d_in[1];    // int64 narrowed to int32
  const float* W1 = (const float*)d_in[2];
  const float* b1 = (const float*)d_in[3];
  const float* W2 = (const float*)d_in[4];
  const float* b2 = (const float*)d_in[5];
  const float* W3 = (const float*)d_in[6];
  const float* b3 = (const float*)d_in[7];
  float* out = (float*)d_out;

  char* ws = (char*)d_ws;
  size_t p = 0;
  auto carve = [&](size_t bytes) -> char* {
    char* r = ws + p;
    p += (bytes + 255) & ~(size_t)255;
    return r;
  };
  int*            bktCur = (int*)           carve((size_t)NBT * 4);
  unsigned int*   rec    = (unsigned int*)  carve((size_t)NBT * CAPQ * 4);  // 14.5MB
  unsigned short* col    = (unsigned short*)carve((size_t)NBT * CAPQ * 2);  // 7.2MB
  int*            off    = (int*)           carve((size_t)NG * (NN + 1) * 4);
  unsigned short* deg    = (unsigned short*)carve((size_t)NG * NN * 2);
  float*          dis    = (float*)         carve((size_t)NG * NN * 4);
  _Float16*       hbuf   = (_Float16*)      carve((size_t)NG * NN * NC * 2);

  init_cursors<<<(NBT + 255) / 256, 256, 0, stream>>>(bktCur);
  bucket_scatter<<<dim3((NE + 4095) / 4096, NG), 256, 0, stream>>>(ei, bktCur, rec);
  build_csr<<<dim3(NB, NG), 256, 0, stream>>>(rec, bktCur, col, off, deg, dis);

  dim3 ggrid((NN + 127) / 128, NG);
  int  agrid = ((NN / 16 + 1) / 2) * 8;   // 1563 * 8 = 12504 (XCD-affine)

  // layer 1: x -> hbuf(fp16, permuted) -> out
  gemm_mfma_kernel<<<ggrid, 256, 0, stream>>>(x, W1, dis, hbuf);
  agg_kernel<<<agrid, 256, 0, stream>>>(hbuf, off, col, deg, dis, b1, out);
  // layer 2: out -> hbuf -> out   (agg reads only hbuf/CSR, overwrite safe)
  gemm_mfma_kernel<<<ggrid, 256, 0, stream>>>(out, W2, dis, hbuf);
  agg_kernel<<<agrid, 256, 0, stream>>>(hbuf, off, col, deg, dis, b2, out);
  // layer 3: out -> hbuf -> out
  gemm_mfma_kernel<<<ggrid, 256, 0, stream>>>(out, W3, dis, hbuf);
  agg_kernel<<<agrid, 256, 0, stream>>>(hbuf, off, col, deg, dis, b3, out);
}

// Round 11
// 459.772 us; speedup vs baseline: 1.7475x; 1.1235x over previous
//
#include <hip/hip_runtime.h>

#define NG 4
#define NN 50000
#define NE 800000
#define NC 128
#define NB 196              // ceil(NN/256) buckets of 256 nodes per graph
#define NBT (NG * NB)       // 784 total buckets
#define CAPB 48             // LDS bin capacity in pass B (lambda~21, +6 sigma)
#define LBS (NB + 1)        // lbin stride 197 (odd -> conflict-free flush)
#define CAPQ 4608           // fixed bucket capacity (lambda 4096, +8 sigma)

typedef _Float16 half8 __attribute__((ext_vector_type(8)));
typedef _Float16 half4 __attribute__((ext_vector_type(4)));
typedef float f32x4 __attribute__((ext_vector_type(4)));

// ---------------------------------------------------------------- utilities
__global__ __launch_bounds__(256) void init_cursors(int* __restrict__ bktCur) {
  int i = blockIdx.x * blockDim.x + threadIdx.x;
  if (i < NBT) bktCur[i] = i * CAPQ;
}

// ------------------------------------------------ CSR build, bucketed sort
__global__ __launch_bounds__(256) void bucket_scatter(
    const int* __restrict__ ei, int* __restrict__ bktCur,
    unsigned int* __restrict__ rec) {
  __shared__ int lcnt[NB];
  __shared__ int lbase[NB];
  __shared__ unsigned int lbin[CAPB * LBS];   // ~37.8 KB
  int g = blockIdx.y;
  int tid = threadIdx.x;
  for (int i = tid; i < NB; i += 256) lcnt[i] = 0;
  __syncthreads();
  const int* srcp = ei + (size_t)g * 2 * NE;
  const int* dstp = srcp + NE;
  int e0 = blockIdx.x * 4096;
  for (int t = tid; t < 4096; t += 256) {
    int e = e0 + t;
    if (e < NE) {
      int s = srcp[e], d = dstp[e];
      int b = d >> 8;
      unsigned int r = ((unsigned int)(d & 255) << 16) | (unsigned int)s;
      int pos = atomicAdd(&lcnt[b], 1);
      if (pos < CAPB) lbin[pos * LBS + b] = r;
      else { int gp = atomicAdd(&bktCur[g * NB + b], 1); rec[gp] = r; }  // rare
    }
  }
  __syncthreads();
  if (tid < NB) {
    int n = lcnt[tid]; if (n > CAPB) n = CAPB;
    lbase[tid] = n ? atomicAdd(&bktCur[g * NB + tid], n) : 0;
  }
  __syncthreads();
  int lane = tid & 63, wv = tid >> 6;
  for (int b = wv; b < NB; b += 4) {
    int n = lcnt[b]; if (n > CAPB) n = CAPB;
    if (lane < n) rec[lbase[b] + lane] = lbin[lane * LBS + b];
  }
}

__global__ __launch_bounds__(256) void build_csr(
    const unsigned int* __restrict__ rec, const int* __restrict__ bktCur,
    unsigned short* __restrict__ col, int* __restrict__ off,
    unsigned short* __restrict__ deg, float* __restrict__ dis) {
  __shared__ int cnt[256];
  __shared__ int offv[256];
  __shared__ int cnt2[256];
  __shared__ int wsum[4];
  int g = blockIdx.y, b = blockIdx.x;
  int idx = g * NB + b;
  int rb = idx * CAPQ, re = bktCur[idx];
  int tid = threadIdx.x;
  cnt[tid] = 0;
  __syncthreads();
  for (int j = rb + tid; j < re; j += 256)
    atomicAdd(&cnt[(rec[j] >> 16) & 255], 1);
  __syncthreads();
  int lane = tid & 63, wv = tid >> 6;
  int v = cnt[tid], incl = v;
  #pragma unroll
  for (int d2 = 1; d2 < 64; d2 <<= 1) {
    int t = __shfl_up(incl, d2, 64);
    if (lane >= d2) incl += t;
  }
  if (lane == 63) wsum[wv] = incl;
  __syncthreads();
  if (tid == 0) {
    int s = 0;
    #pragma unroll
    for (int w = 0; w < 4; ++w) { int t = wsum[w]; wsum[w] = s; s += t; }
  }
  __syncthreads();
  int excl = wsum[wv] + incl - v;
  offv[tid] = excl;
  cnt2[tid] = 0;
  int node = b * 256 + tid;
  if (node < NN) {
    off[g * (NN + 1) + node] = rb + excl;
    deg[(size_t)g * NN + node] = (unsigned short)v;
    dis[(size_t)g * NN + node] = rsqrtf((float)(v + 1));  // +1 self loop
  }
  __syncthreads();
  for (int j = rb + tid; j < re; j += 256) {
    unsigned int r = rec[j];
    int dl = (r >> 16) & 255;
    int p = rb + offv[dl] + atomicAdd(&cnt2[dl], 1);
    col[p] = (unsigned short)(r & 0xFFFF);
  }
}

// ---------------------------------------------------- MFMA GEMM  h'=(x@W)*dis
// fp32-input variant (layer 1): x split hi+lo fp16, W split hi+lo, 3 MFMAs.
// h' written fp16 permuted: slot lr*8+nb holds true col nb*16+lr.
__global__ __launch_bounds__(256) void gemm_mfma_kernel(
    const float* __restrict__ x, const float* __restrict__ W,
    const float* __restrict__ dis, _Float16* __restrict__ h) {
  __shared__ _Float16 Wt[2][128 * 128];
  int g = blockIdx.y;
  int row0 = blockIdx.x * 128;
  int tid = threadIdx.x;
  int lane = tid & 63;
  int wv = tid >> 6;
  int kc = lane >> 4;
  int lr = lane & 15;
  const float* Wg = W + (size_t)g * NC * NC;
  const float* xg = x + (size_t)g * NN * NC;

  {
    int n = tid & 127;
    int kq = (tid >> 7) & 1;
    #pragma unroll
    for (int iter = 0; iter < 16; ++iter) {
      int k4 = iter * 8 + kq * 4;
      float w0 = Wg[(size_t)(k4 + 0) * NC + n];
      float w1 = Wg[(size_t)(k4 + 1) * NC + n];
      float w2 = Wg[(size_t)(k4 + 2) * NC + n];
      float w3 = Wg[(size_t)(k4 + 3) * NC + n];
      half4 hi, lo;
      hi[0] = (_Float16)w0; lo[0] = (_Float16)(w0 - (float)hi[0]);
      hi[1] = (_Float16)w1; lo[1] = (_Float16)(w1 - (float)hi[1]);
      hi[2] = (_Float16)w2; lo[2] = (_Float16)(w2 - (float)hi[2]);
      hi[3] = (_Float16)w3; lo[3] = (_Float16)(w3 - (float)hi[3]);
      int base = n * 128 + ((iter ^ (n & 15)) << 3) + kq * 4;
      *(half4*)&Wt[0][base] = hi;
      *(half4*)&Wt[1][base] = lo;
    }
  }
  __syncthreads();

  f32x4 acc[2][8];
  #pragma unroll
  for (int mb = 0; mb < 2; ++mb)
    #pragma unroll
    for (int nb = 0; nb < 8; ++nb)
      acc[mb][nb] = (f32x4){0.f, 0.f, 0.f, 0.f};

  for (int kstep = 0; kstep < 4; ++kstep) {
    half8 ah[2], al[2];
    #pragma unroll
    for (int mb = 0; mb < 2; ++mb) {
      int row = row0 + wv * 32 + mb * 16 + lr;
      if (row > NN - 1) row = NN - 1;
      const float* xp = xg + (size_t)row * NC + kstep * 32 + kc * 8;
      float4 v0 = *(const float4*)xp;
      float4 v1 = *(const float4*)(xp + 4);
      float vv0 = v0.x, vv1 = v0.y, vv2 = v0.z, vv3 = v0.w;
      float vv4 = v1.x, vv5 = v1.y, vv6 = v1.z, vv7 = v1.w;
      _Float16 t;
      t = (_Float16)vv0; ah[mb][0] = t; al[mb][0] = (_Float16)(vv0 - (float)t);
      t = (_Float16)vv1; ah[mb][1] = t; al[mb][1] = (_Float16)(vv1 - (float)t);
      t = (_Float16)vv2; ah[mb][2] = t; al[mb][2] = (_Float16)(vv2 - (float)t);
      t = (_Float16)vv3; ah[mb][3] = t; al[mb][3] = (_Float16)(vv3 - (float)t);
      t = (_Float16)vv4; ah[mb][4] = t; al[mb][4] = (_Float16)(vv4 - (float)t);
      t = (_Float16)vv5; ah[mb][5] = t; al[mb][5] = (_Float16)(vv5 - (float)t);
      t = (_Float16)vv6; ah[mb][6] = t; al[mb][6] = (_Float16)(vv6 - (float)t);
      t = (_Float16)vv7; ah[mb][7] = t; al[mb][7] = (_Float16)(vv7 - (float)t);
    }
    #pragma unroll
    for (int nb = 0; nb < 8; ++nb) {
      int n = nb * 16 + lr;
      int chunk = kstep * 4 + kc;
      int boff = n * 128 + ((chunk ^ (n & 15)) << 3);
      half8 bh = *(const half8*)&Wt[0][boff];
      half8 bl = *(const half8*)&Wt[1][boff];
      #pragma unroll
      for (int mb = 0; mb < 2; ++mb) {
        acc[mb][nb] = __builtin_amdgcn_mfma_f32_16x16x32_f16(ah[mb], bh, acc[mb][nb], 0, 0, 0);
        acc[mb][nb] = __builtin_amdgcn_mfma_f32_16x16x32_f16(al[mb], bh, acc[mb][nb], 0, 0, 0);
        acc[mb][nb] = __builtin_amdgcn_mfma_f32_16x16x32_f16(ah[mb], bl, acc[mb][nb], 0, 0, 0);
      }
    }
  }

  const float* disg = dis + (size_t)g * NN;
  _Float16* hg = h + (size_t)g * NN * NC;
  #pragma unroll
  for (int mb = 0; mb < 2; ++mb) {
    #pragma unroll
    for (int reg = 0; reg < 4; ++reg) {
      int row = row0 + wv * 32 + mb * 16 + kc * 4 + reg;
      if (row < NN) {
        float dsc = disg[row];
        half8 o;
        #pragma unroll
        for (int nb = 0; nb < 8; ++nb)
          o[nb] = (_Float16)(acc[mb][nb][reg] * dsc);
        *(half8*)(hg + (size_t)row * NC + lr * 8) = o;
      }
    }
  }
}

// fp16-input variant (layers 2,3): x already fp16 (true row-major), A-frag is
// one contiguous half8 load, no split -> 2 MFMAs per fragment.
__global__ __launch_bounds__(256) void gemm16_mfma_kernel(
    const _Float16* __restrict__ x, const float* __restrict__ W,
    const float* __restrict__ dis, _Float16* __restrict__ h) {
  __shared__ _Float16 Wt[2][128 * 128];
  int g = blockIdx.y;
  int row0 = blockIdx.x * 128;
  int tid = threadIdx.x;
  int lane = tid & 63;
  int wv = tid >> 6;
  int kc = lane >> 4;
  int lr = lane & 15;
  const float* Wg = W + (size_t)g * NC * NC;
  const _Float16* xg = x + (size_t)g * NN * NC;

  {
    int n = tid & 127;
    int kq = (tid >> 7) & 1;
    #pragma unroll
    for (int iter = 0; iter < 16; ++iter) {
      int k4 = iter * 8 + kq * 4;
      float w0 = Wg[(size_t)(k4 + 0) * NC + n];
      float w1 = Wg[(size_t)(k4 + 1) * NC + n];
      float w2 = Wg[(size_t)(k4 + 2) * NC + n];
      float w3 = Wg[(size_t)(k4 + 3) * NC + n];
      half4 hi, lo;
      hi[0] = (_Float16)w0; lo[0] = (_Float16)(w0 - (float)hi[0]);
      hi[1] = (_Float16)w1; lo[1] = (_Float16)(w1 - (float)hi[1]);
      hi[2] = (_Float16)w2; lo[2] = (_Float16)(w2 - (float)hi[2]);
      hi[3] = (_Float16)w3; lo[3] = (_Float16)(w3 - (float)hi[3]);
      int base = n * 128 + ((iter ^ (n & 15)) << 3) + kq * 4;
      *(half4*)&Wt[0][base] = hi;
      *(half4*)&Wt[1][base] = lo;
    }
  }
  __syncthreads();

  f32x4 acc[2][8];
  #pragma unroll
  for (int mb = 0; mb < 2; ++mb)
    #pragma unroll
    for (int nb = 0; nb < 8; ++nb)
      acc[mb][nb] = (f32x4){0.f, 0.f, 0.f, 0.f};

  for (int kstep = 0; kstep < 4; ++kstep) {
    half8 ah[2];
    #pragma unroll
    for (int mb = 0; mb < 2; ++mb) {
      int row = row0 + wv * 32 + mb * 16 + lr;
      if (row > NN - 1) row = NN - 1;
      ah[mb] = *(const half8*)(xg + (size_t)row * NC + kstep * 32 + kc * 8);
    }
    #pragma unroll
    for (int nb = 0; nb < 8; ++nb) {
      int n = nb * 16 + lr;
      int chunk = kstep * 4 + kc;
      int boff = n * 128 + ((chunk ^ (n & 15)) << 3);
      half8 bh = *(const half8*)&Wt[0][boff];
      half8 bl = *(const half8*)&Wt[1][boff];
      #pragma unroll
      for (int mb = 0; mb < 2; ++mb) {
        acc[mb][nb] = __builtin_amdgcn_mfma_f32_16x16x32_f16(ah[mb], bh, acc[mb][nb], 0, 0, 0);
        acc[mb][nb] = __builtin_amdgcn_mfma_f32_16x16x32_f16(ah[mb], bl, acc[mb][nb], 0, 0, 0);
      }
    }
  }

  const float* disg = dis + (size_t)g * NN;
  _Float16* hg = h + (size_t)g * NN * NC;
  #pragma unroll
  for (int mb = 0; mb < 2; ++mb) {
    #pragma unroll
    for (int reg = 0; reg < 4; ++reg) {
      int row = row0 + wv * 32 + mb * 16 + kc * 4 + reg;
      if (row < NN) {
        float dsc = disg[row];
        half8 o;
        #pragma unroll
        for (int nb = 0; nb < 8; ++nb)
          o[nb] = (_Float16)(acc[mb][nb][reg] * dsc);
        *(half8*)(hg + (size_t)row * NC + lr * 8) = o;
      }
    }
  }
}

// --------------------------------------------- aggregation: gather over CSR
// out[i] = dis[i]*(h'[i] + sum_{e} h'[src_e]) + b.  4-deep chains (R8 body).
// F16OUT: store fp16 true-row-major xh (layers 1,2) for gemm16; else fp32 d_out.
#define MIXACC(A, H) A = fmaf((float)(H), 1.0f, A)
template <bool F16OUT>
__global__ __launch_bounds__(256) void agg_kernel(
    const _Float16* __restrict__ h, const int* __restrict__ off,
    const unsigned short* __restrict__ col, const unsigned short* __restrict__ deg,
    const float* __restrict__ dis, const float* __restrict__ b,
    float* __restrict__ outf, _Float16* __restrict__ outh) {
  int bid = blockIdx.x;
  int g = (bid & 7) >> 1;                        // graph -> XCD pair
  int sub = ((bid >> 3) << 1) | (bid & 1);       // block index within graph
  int node = sub * 16 + (threadIdx.x >> 4);
  if (sub >= NN / 16) return;
  int l = threadIdx.x & 15;
  const half8* h8 = (const half8*)(h + (size_t)g * NN * NC);
  float a0[8], a1[8], a2[8], a3[8];
  half8 v = h8[(size_t)node * 16 + l];   // self loop
  #pragma unroll
  for (int i = 0; i < 8; ++i) {
    a0[i] = (float)v[i]; a1[i] = 0.f; a2[i] = 0.f; a3[i] = 0.f;
  }
  int s = off[g * (NN + 1) + node];
  int e = s + deg[(size_t)g * NN + node];
  int j = s;
  for (; j + 4 <= e; j += 4) {
    int c0 = col[j], c1 = col[j + 1], c2 = col[j + 2], c3 = col[j + 3];
    half8 v0 = h8[(size_t)c0 * 16 + l];
    half8 v1 = h8[(size_t)c1 * 16 + l];
    half8 v2 = h8[(size_t)c2 * 16 + l];
    half8 v3 = h8[(size_t)c3 * 16 + l];
    #pragma unroll
    for (int i = 0; i < 8; ++i) {
      MIXACC(a0[i], v0[i]); MIXACC(a1[i], v1[i]);
      MIXACC(a2[i], v2[i]); MIXACC(a3[i], v3[i]);
    }
  }
  for (; j < e; ++j) {
    half8 vr = h8[(size_t)col[j] * 16 + l];
    #pragma unroll
    for (int i = 0; i < 8; ++i) MIXACC(a0[i], vr[i]);
  }
  float dn = dis[g * NN + node];
  const float* bg = b + (size_t)g * NC;
  if constexpr (F16OUT) {
    _Float16* og = outh + ((size_t)g * NN + node) * NC;
    #pragma unroll
    for (int i = 0; i < 8; ++i) {   // true col c = i*16 + l (row-major store)
      float val = (a0[i] + a1[i] + a2[i] + a3[i]) * dn + bg[i * 16 + l];
      og[i * 16 + l] = (_Float16)val;
    }
  } else {
    float* og = outf + ((size_t)g * NN + node) * NC;
    #pragma unroll
    for (int i = 0; i < 8; ++i) {
      float val = (a0[i] + a1[i] + a2[i] + a3[i]) * dn + bg[i * 16 + l];
      og[i * 16 + l] = val;
    }
  }
}

// ---------------------------------------------------------------- launcher
extern "C" void kernel_launch(void* const* d_in, const int* in_sizes, int n_in,
                              void* d_out, int out_size, void* d_ws, size_t ws_size,
                              hipStream_t stream) {
  const float* x  = (const float*)d_in[0];
  const int*   ei = (const int*)d_in[1];    // int64 narrowed to int32
  const float* W1 = (const float*)d_in[2];
  const float* b1 = (const float*)d_in[3];
  const float* W2 = (const float*)d_in[4];
  const float* b2 = (const float*)d_in[5];
  const float* W3 = (const float*)d_in[6];
  const float* b3 = (const float*)d_in[7];
  float* out = (float*)d_out;

  char* ws = (char*)d_ws;
  size_t p = 0;
  auto carve = [&](size_t bytes) -> char* {
    char* r = ws + p;
    p += (bytes + 255) & ~(size_t)255;
    return r;
  };
  int*            bktCur = (int*)           carve((size_t)NBT * 4);
  unsigned short* col    = (unsigned short*)carve((size_t)NBT * CAPQ * 2);  // 7.2MB
  int*            off    = (int*)           carve((size_t)NG * (NN + 1) * 4);
  unsigned short* deg    = (unsigned short*)carve((size_t)NG * NN * 2);
  float*          dis    = (float*)         carve((size_t)NG * NN * 4);
  _Float16*       hbuf   = (_Float16*)      carve((size_t)NG * NN * NC * 2); // 51.2MB
  // union region: rec (CSR build, dead after build_csr) | xh (inter-layer fp16)
  size_t ubytes = (size_t)NG * NN * NC * 2;                  // 51.2MB >= rec 14.5MB
  char*           uni    = carve(ubytes);
  unsigned int*   rec    = (unsigned int*)uni;
  _Float16*       xh     = (_Float16*)uni;

  init_cursors<<<(NBT + 255) / 256, 256, 0, stream>>>(bktCur);
  bucket_scatter<<<dim3((NE + 4095) / 4096, NG), 256, 0, stream>>>(ei, bktCur, rec);
  build_csr<<<dim3(NB, NG), 256, 0, stream>>>(rec, bktCur, col, off, deg, dis);

  dim3 ggrid((NN + 127) / 128, NG);
  int  agrid = ((NN / 16 + 1) / 2) * 8;   // 1563 * 8 = 12504 (XCD-affine)

  // layer 1: x(f32) -> hbuf -> xh(f16)     [xh overwrites dead rec]
  gemm_mfma_kernel<<<ggrid, 256, 0, stream>>>(x, W1, dis, hbuf);
  agg_kernel<true><<<agrid, 256, 0, stream>>>(hbuf, off, col, deg, dis, b1, nullptr, xh);
  // layer 2: xh -> hbuf -> xh   (gemm16 reads xh before agg overwrites it)
  gemm16_mfma_kernel<<<ggrid, 256, 0, stream>>>(xh, W2, dis, hbuf);
  agg_kernel<true><<<agrid, 256, 0, stream>>>(hbuf, off, col, deg, dis, b2, nullptr, xh);
  // layer 3: xh -> hbuf -> out(f32)
  gemm16_mfma_kernel<<<ggrid, 256, 0, stream>>>(xh, W3, dis, hbuf);
  agg_kernel<false><<<agrid, 256, 0, stream>>>(hbuf, off, col, deg, dis, b3, out, nullptr);
}

// Round 12
// 443.629 us; speedup vs baseline: 1.8110x; 1.0364x over previous
//
#include <hip/hip_runtime.h>

#define NG 4
#define NN 50000
#define NE 800000
#define NC 128
#define NB 196              // ceil(NN/256) buckets of 256 nodes per graph
#define NBT (NG * NB)       // 784 total buckets
#define CAPB 48             // LDS bin capacity in scatter (lambda~21, +6 sigma)
#define LBS (NB + 1)        // lbin stride 197 (odd -> conflict-free flush)
#define CAPQ 4608           // fixed bucket capacity (lambda 4096, +8 sigma)
#define GEMM_BLKS 784       // 196 row-tiles (256 rows) x 4 graphs

typedef _Float16 half8 __attribute__((ext_vector_type(8)));
typedef _Float16 half4 __attribute__((ext_vector_type(4)));
typedef float f32x4 __attribute__((ext_vector_type(4)));

// ---------------------------------------------------------------- utilities
__global__ __launch_bounds__(256) void init_cursors(int* __restrict__ bktCur) {
  int i = blockIdx.x * blockDim.x + threadIdx.x;
  if (i < NBT) bktCur[i] = i * CAPQ;
}

// ---------------- FAT kernel: [gemm L1 (unscaled h'')]  ||  [bucket_scatter]
// gemm: 512 thr, 8 waves, tile 256 rows x 128 cols; x fp32 split hi/lo fp16,
// W split hi/lo, 3 MFMAs/frag. Epilogue: NO dis scale (applied in agg L1).
// scatter: LDS bins [pos][bucket] stride 197; parallel reserve; clean flush.
// LDS union: gemm Wt 64KB | scatter lcnt/lbase/lbin ~40KB.
__global__ __launch_bounds__(512) void fat_gemm1_scatter(
    const float* __restrict__ x, const float* __restrict__ W,
    _Float16* __restrict__ h, const int* __restrict__ ei,
    int* __restrict__ bktCur, unsigned int* __restrict__ rec) {
  __shared__ char smem[65536];
  int bid = blockIdx.x;
  int tid = threadIdx.x;
  if (bid < GEMM_BLKS) {
    _Float16* Wt0 = (_Float16*)smem;
    _Float16* Wt1 = Wt0 + 128 * 128;
    int g = bid / 196;
    int row0 = (bid % 196) * 256;
    int lane = tid & 63;
    int wv = tid >> 6;          // 0..7
    int kc = lane >> 4;
    int lr = lane & 15;
    const float* Wg = W + (size_t)g * NC * NC;
    const float* xg = x + (size_t)g * NN * NC;
    {
      int n = tid & 127;
      int kq = (tid >> 7) & 3;
      #pragma unroll
      for (int it = 0; it < 8; ++it) {
        int k4 = it * 16 + kq * 4;
        float w0 = Wg[(size_t)(k4 + 0) * NC + n];
        float w1 = Wg[(size_t)(k4 + 1) * NC + n];
        float w2 = Wg[(size_t)(k4 + 2) * NC + n];
        float w3 = Wg[(size_t)(k4 + 3) * NC + n];
        half4 hi, lo;
        hi[0] = (_Float16)w0; lo[0] = (_Float16)(w0 - (float)hi[0]);
        hi[1] = (_Float16)w1; lo[1] = (_Float16)(w1 - (float)hi[1]);
        hi[2] = (_Float16)w2; lo[2] = (_Float16)(w2 - (float)hi[2]);
        hi[3] = (_Float16)w3; lo[3] = (_Float16)(w3 - (float)hi[3]);
        int chunk = k4 >> 3;
        int base = n * 128 + ((chunk ^ (n & 15)) << 3) + (k4 & 4);
        *(half4*)&Wt0[base] = hi;
        *(half4*)&Wt1[base] = lo;
      }
    }
    __syncthreads();
    f32x4 acc[2][8];
    #pragma unroll
    for (int mb = 0; mb < 2; ++mb)
      #pragma unroll
      for (int nb = 0; nb < 8; ++nb)
        acc[mb][nb] = (f32x4){0.f, 0.f, 0.f, 0.f};
    for (int kstep = 0; kstep < 4; ++kstep) {
      half8 ah[2], al[2];
      #pragma unroll
      for (int mb = 0; mb < 2; ++mb) {
        int row = row0 + wv * 32 + mb * 16 + lr;
        if (row > NN - 1) row = NN - 1;
        const float* xp = xg + (size_t)row * NC + kstep * 32 + kc * 8;
        float4 v0 = *(const float4*)xp;
        float4 v1 = *(const float4*)(xp + 4);
        float vv[8] = {v0.x, v0.y, v0.z, v0.w, v1.x, v1.y, v1.z, v1.w};
        #pragma unroll
        for (int i = 0; i < 8; ++i) {
          _Float16 t = (_Float16)vv[i];
          ah[mb][i] = t; al[mb][i] = (_Float16)(vv[i] - (float)t);
        }
      }
      #pragma unroll
      for (int nb = 0; nb < 8; ++nb) {
        int n = nb * 16 + lr;
        int chunk = kstep * 4 + kc;
        int boff = n * 128 + ((chunk ^ (n & 15)) << 3);
        half8 bh = *(const half8*)&Wt0[boff];
        half8 bl = *(const half8*)&Wt1[boff];
        #pragma unroll
        for (int mb = 0; mb < 2; ++mb) {
          acc[mb][nb] = __builtin_amdgcn_mfma_f32_16x16x32_f16(ah[mb], bh, acc[mb][nb], 0, 0, 0);
          acc[mb][nb] = __builtin_amdgcn_mfma_f32_16x16x32_f16(al[mb], bh, acc[mb][nb], 0, 0, 0);
          acc[mb][nb] = __builtin_amdgcn_mfma_f32_16x16x32_f16(ah[mb], bl, acc[mb][nb], 0, 0, 0);
        }
      }
    }
    _Float16* hg = h + (size_t)g * NN * NC;
    #pragma unroll
    for (int mb = 0; mb < 2; ++mb) {
      #pragma unroll
      for (int reg = 0; reg < 4; ++reg) {
        int row = row0 + wv * 32 + mb * 16 + kc * 4 + reg;
        if (row < NN) {
          half8 o;
          #pragma unroll
          for (int nb = 0; nb < 8; ++nb)
            o[nb] = (_Float16)acc[mb][nb][reg];     // UNSCALED h''
          *(half8*)(hg + (size_t)row * NC + lr * 8) = o;
        }
      }
    }
  } else {
    int* lcnt = (int*)smem;
    int* lbase = lcnt + NB;
    unsigned int* lbin = (unsigned int*)(smem + 2048);   // 37824B, fits
    int sb = bid - GEMM_BLKS;
    int g = sb / 196;
    int e0 = (sb % 196) * 4096;
    for (int i = tid; i < NB; i += 512) lcnt[i] = 0;
    __syncthreads();
    const int* srcp = ei + (size_t)g * 2 * NE;
    const int* dstp = srcp + NE;
    for (int t = tid; t < 4096; t += 512) {
      int e = e0 + t;
      if (e < NE) {
        int s = srcp[e], d = dstp[e];
        int b = d >> 8;
        unsigned int r = ((unsigned int)(d & 255) << 16) | (unsigned int)s;
        int pos = atomicAdd(&lcnt[b], 1);
        if (pos < CAPB) lbin[pos * LBS + b] = r;
        else { int gp = atomicAdd(&bktCur[g * NB + b], 1); rec[gp] = r; }  // rare
      }
    }
    __syncthreads();
    if (tid < NB) {
      int n = lcnt[tid]; if (n > CAPB) n = CAPB;
      lbase[tid] = n ? atomicAdd(&bktCur[g * NB + tid], n) : 0;
    }
    __syncthreads();
    int lane = tid & 63, wv = tid >> 6;
    for (int b = wv; b < NB; b += 8) {
      int n = lcnt[b]; if (n > CAPB) n = CAPB;
      if (lane < n) rec[lbase[b] + lane] = lbin[lane * LBS + b];
    }
  }
}

// Per (graph,bucket): LDS count -> scan -> rank into padded col[]. off/deg/dis.
__global__ __launch_bounds__(256) void build_csr(
    const unsigned int* __restrict__ rec, const int* __restrict__ bktCur,
    unsigned short* __restrict__ col, int* __restrict__ off,
    unsigned short* __restrict__ deg, float* __restrict__ dis) {
  __shared__ int cnt[256];
  __shared__ int offv[256];
  __shared__ int cnt2[256];
  __shared__ int wsum[4];
  int g = blockIdx.y, b = blockIdx.x;
  int idx = g * NB + b;
  int rb = idx * CAPQ, re = bktCur[idx];
  int tid = threadIdx.x;
  cnt[tid] = 0;
  __syncthreads();
  for (int j = rb + tid; j < re; j += 256)
    atomicAdd(&cnt[(rec[j] >> 16) & 255], 1);
  __syncthreads();
  int lane = tid & 63, wv = tid >> 6;
  int v = cnt[tid], incl = v;
  #pragma unroll
  for (int d2 = 1; d2 < 64; d2 <<= 1) {
    int t = __shfl_up(incl, d2, 64);
    if (lane >= d2) incl += t;
  }
  if (lane == 63) wsum[wv] = incl;
  __syncthreads();
  if (tid == 0) {
    int s = 0;
    #pragma unroll
    for (int w = 0; w < 4; ++w) { int t = wsum[w]; wsum[w] = s; s += t; }
  }
  __syncthreads();
  int excl = wsum[wv] + incl - v;
  offv[tid] = excl;
  cnt2[tid] = 0;
  int node = b * 256 + tid;
  if (node < NN) {
    off[g * (NN + 1) + node] = rb + excl;
    deg[(size_t)g * NN + node] = (unsigned short)v;
    dis[(size_t)g * NN + node] = rsqrtf((float)(v + 1));  // +1 self loop
  }
  __syncthreads();
  for (int j = rb + tid; j < re; j += 256) {
    unsigned int r = rec[j];
    int dl = (r >> 16) & 255;
    int p = rb + offv[dl] + atomicAdd(&cnt2[dl], 1);
    col[p] = (unsigned short)(r & 0xFFFF);
  }
}

// -------------------- fp16-input GEMM (layers 2,3): 512 thr, 256-row tile,
// WITH dis scale (inputs already normalized). 2 MFMAs/frag.
__global__ __launch_bounds__(512) void gemm16_mfma_kernel(
    const _Float16* __restrict__ x, const float* __restrict__ W,
    const float* __restrict__ dis, _Float16* __restrict__ h) {
  __shared__ _Float16 Wt[2][128 * 128];
  int g = blockIdx.y;
  int row0 = blockIdx.x * 256;
  int tid = threadIdx.x;
  int lane = tid & 63;
  int wv = tid >> 6;            // 0..7
  int kc = lane >> 4;
  int lr = lane & 15;
  const float* Wg = W + (size_t)g * NC * NC;
  const _Float16* xg = x + (size_t)g * NN * NC;
  {
    int n = tid & 127;
    int kq = (tid >> 7) & 3;
    #pragma unroll
    for (int it = 0; it < 8; ++it) {
      int k4 = it * 16 + kq * 4;
      float w0 = Wg[(size_t)(k4 + 0) * NC + n];
      float w1 = Wg[(size_t)(k4 + 1) * NC + n];
      float w2 = Wg[(size_t)(k4 + 2) * NC + n];
      float w3 = Wg[(size_t)(k4 + 3) * NC + n];
      half4 hi, lo;
      hi[0] = (_Float16)w0; lo[0] = (_Float16)(w0 - (float)hi[0]);
      hi[1] = (_Float16)w1; lo[1] = (_Float16)(w1 - (float)hi[1]);
      hi[2] = (_Float16)w2; lo[2] = (_Float16)(w2 - (float)hi[2]);
      hi[3] = (_Float16)w3; lo[3] = (_Float16)(w3 - (float)hi[3]);
      int chunk = k4 >> 3;
      int base = n * 128 + ((chunk ^ (n & 15)) << 3) + (k4 & 4);
      *(half4*)&Wt[0][base] = hi;
      *(half4*)&Wt[1][base] = lo;
    }
  }
  __syncthreads();
  f32x4 acc[2][8];
  #pragma unroll
  for (int mb = 0; mb < 2; ++mb)
    #pragma unroll
    for (int nb = 0; nb < 8; ++nb)
      acc[mb][nb] = (f32x4){0.f, 0.f, 0.f, 0.f};
  for (int kstep = 0; kstep < 4; ++kstep) {
    half8 ah[2];
    #pragma unroll
    for (int mb = 0; mb < 2; ++mb) {
      int row = row0 + wv * 32 + mb * 16 + lr;
      if (row > NN - 1) row = NN - 1;
      ah[mb] = *(const half8*)(xg + (size_t)row * NC + kstep * 32 + kc * 8);
    }
    #pragma unroll
    for (int nb = 0; nb < 8; ++nb) {
      int n = nb * 16 + lr;
      int chunk = kstep * 4 + kc;
      int boff = n * 128 + ((chunk ^ (n & 15)) << 3);
      half8 bh = *(const half8*)&Wt[0][boff];
      half8 bl = *(const half8*)&Wt[1][boff];
      #pragma unroll
      for (int mb = 0; mb < 2; ++mb) {
        acc[mb][nb] = __builtin_amdgcn_mfma_f32_16x16x32_f16(ah[mb], bh, acc[mb][nb], 0, 0, 0);
        acc[mb][nb] = __builtin_amdgcn_mfma_f32_16x16x32_f16(ah[mb], bl, acc[mb][nb], 0, 0, 0);
      }
    }
  }
  const float* disg = dis + (size_t)g * NN;
  _Float16* hg = h + (size_t)g * NN * NC;
  #pragma unroll
  for (int mb = 0; mb < 2; ++mb) {
    #pragma unroll
    for (int reg = 0; reg < 4; ++reg) {
      int row = row0 + wv * 32 + mb * 16 + kc * 4 + reg;
      if (row < NN) {
        float dsc = disg[row];
        half8 o;
        #pragma unroll
        for (int nb = 0; nb < 8; ++nb)
          o[nb] = (_Float16)(acc[mb][nb][reg] * dsc);
        *(half8*)(hg + (size_t)row * NC + lr * 8) = o;
      }
    }
  }
}

// --------------------------------------------- aggregation: gather over CSR
// GDIS=false (h' pre-scaled): out = dis[i]*(h'[i] + sum h'[s]) + b
// GDIS=true (h'' unscaled):  out = dis[i]*(dis[i]*h''[i] + sum dis[s]*h''[s]) + b
// 16 lanes/node, 4-deep chains, v_fma_mix accumulate.
#define MIXACC(A, H) A = fmaf((float)(H), 1.0f, A)
#define MIXS(A, H, S) A = fmaf((float)(H), S, A)
template <bool F16OUT, bool GDIS>
__global__ __launch_bounds__(256) void agg_kernel(
    const _Float16* __restrict__ h, const int* __restrict__ off,
    const unsigned short* __restrict__ col, const unsigned short* __restrict__ deg,
    const float* __restrict__ dis, const float* __restrict__ b,
    float* __restrict__ outf, _Float16* __restrict__ outh) {
  int bid = blockIdx.x;
  int g = (bid & 7) >> 1;                        // graph -> XCD pair
  int sub = ((bid >> 3) << 1) | (bid & 1);       // block index within graph
  int node = sub * 16 + (threadIdx.x >> 4);
  if (sub >= NN / 16) return;
  int l = threadIdx.x & 15;
  const half8* h8 = (const half8*)(h + (size_t)g * NN * NC);
  const float* disg = dis + (size_t)g * NN;
  float dn = disg[node];
  float a0[8], a1[8], a2[8], a3[8];
  half8 v = h8[(size_t)node * 16 + l];   // self loop
  #pragma unroll
  for (int i = 0; i < 8; ++i) {
    a0[i] = GDIS ? dn * (float)v[i] : (float)v[i];
    a1[i] = 0.f; a2[i] = 0.f; a3[i] = 0.f;
  }
  int s = off[g * (NN + 1) + node];
  int e = s + deg[(size_t)g * NN + node];
  int j = s;
  for (; j + 4 <= e; j += 4) {
    int c0 = col[j], c1 = col[j + 1], c2 = col[j + 2], c3 = col[j + 3];
    half8 v0 = h8[(size_t)c0 * 16 + l];
    half8 v1 = h8[(size_t)c1 * 16 + l];
    half8 v2 = h8[(size_t)c2 * 16 + l];
    half8 v3 = h8[(size_t)c3 * 16 + l];
    if constexpr (GDIS) {
      float d0 = disg[c0], d1 = disg[c1], d2 = disg[c2], d3 = disg[c3];
      #pragma unroll
      for (int i = 0; i < 8; ++i) {
        MIXS(a0[i], v0[i], d0); MIXS(a1[i], v1[i], d1);
        MIXS(a2[i], v2[i], d2); MIXS(a3[i], v3[i], d3);
      }
    } else {
      #pragma unroll
      for (int i = 0; i < 8; ++i) {
        MIXACC(a0[i], v0[i]); MIXACC(a1[i], v1[i]);
        MIXACC(a2[i], v2[i]); MIXACC(a3[i], v3[i]);
      }
    }
  }
  for (; j < e; ++j) {
    int c = col[j];
    half8 vr = h8[(size_t)c * 16 + l];
    if constexpr (GDIS) {
      float dd = disg[c];
      #pragma unroll
      for (int i = 0; i < 8; ++i) MIXS(a0[i], vr[i], dd);
    } else {
      #pragma unroll
      for (int i = 0; i < 8; ++i) MIXACC(a0[i], vr[i]);
    }
  }
  const float* bg = b + (size_t)g * NC;
  if constexpr (F16OUT) {
    _Float16* og = outh + ((size_t)g * NN + node) * NC;
    #pragma unroll
    for (int i = 0; i < 8; ++i) {   // true col c = i*16 + l
      float val = (a0[i] + a1[i] + a2[i] + a3[i]) * dn + bg[i * 16 + l];
      og[i * 16 + l] = (_Float16)val;
    }
  } else {
    float* og = outf + ((size_t)g * NN + node) * NC;
    #pragma unroll
    for (int i = 0; i < 8; ++i) {
      float val = (a0[i] + a1[i] + a2[i] + a3[i]) * dn + bg[i * 16 + l];
      og[i * 16 + l] = val;
    }
  }
}

// ---------------------------------------------------------------- launcher
extern "C" void kernel_launch(void* const* d_in, const int* in_sizes, int n_in,
                              void* d_out, int out_size, void* d_ws, size_t ws_size,
                              hipStream_t stream) {
  const float* x  = (const float*)d_in[0];
  const int*   ei = (const int*)d_in[1];    // int64 narrowed to int32
  const float* W1 = (const float*)d_in[2];
  const float* b1 = (const float*)d_in[3];
  const float* W2 = (const float*)d_in[4];
  const float* b2 = (const float*)d_in[5];
  const float* W3 = (const float*)d_in[6];
  const float* b3 = (const float*)d_in[7];
  float* out = (float*)d_out;

  char* ws = (char*)d_ws;
  size_t p = 0;
  auto carve = [&](size_t bytes) -> char* {
    char* r = ws + p;
    p += (bytes + 255) & ~(size_t)255;
    return r;
  };
  int*            bktCur = (int*)           carve((size_t)NBT * 4);
  unsigned short* col    = (unsigned short*)carve((size_t)NBT * CAPQ * 2);  // 7.2MB
  int*            off    = (int*)           carve((size_t)NG * (NN + 1) * 4);
  unsigned short* deg    = (unsigned short*)carve((size_t)NG * NN * 2);
  float*          dis    = (float*)         carve((size_t)NG * NN * 4);
  _Float16*       hbuf   = (_Float16*)      carve((size_t)NG * NN * NC * 2); // 51.2MB
  // union region: rec (CSR build, dead after build_csr) | xh (inter-layer fp16)
  size_t ubytes = (size_t)NG * NN * NC * 2;                  // 51.2MB >= rec 14.5MB
  char*           uni    = carve(ubytes);
  unsigned int*   rec    = (unsigned int*)uni;
  _Float16*       xh     = (_Float16*)uni;

  init_cursors<<<(NBT + 255) / 256, 256, 0, stream>>>(bktCur);
  // layer-1 GEMM (independent of CSR) overlapped with edge scatter
  fat_gemm1_scatter<<<GEMM_BLKS + 784, 512, 0, stream>>>(x, W1, hbuf, ei, bktCur, rec);
  build_csr<<<dim3(NB, NG), 256, 0, stream>>>(rec, bktCur, col, off, deg, dis);

  dim3 ggrid((NN + 255) / 256, NG);
  int  agrid = ((NN / 16 + 1) / 2) * 8;   // 1563 * 8 = 12504 (XCD-affine)

  // layer 1: hbuf(h'' unscaled) -> xh(f16)  [agg applies dis at gather]
  agg_kernel<true, true><<<agrid, 256, 0, stream>>>(hbuf, off, col, deg, dis, b1, nullptr, xh);
  // layer 2: xh -> hbuf(scaled) -> xh
  gemm16_mfma_kernel<<<ggrid, 512, 0, stream>>>(xh, W2, dis, hbuf);
  agg_kernel<true, false><<<agrid, 256, 0, stream>>>(hbuf, off, col, deg, dis, b2, nullptr, xh);
  // layer 3: xh -> hbuf(scaled) -> out(f32)
  gemm16_mfma_kernel<<<ggrid, 512, 0, stream>>>(xh, W3, dis, hbuf);
  agg_kernel<false, false><<<agrid, 256, 0, stream>>>(hbuf, off, col, deg, dis, b3, out, nullptr);
}